// Round 7
// baseline (37059.567 us; speedup 1.0000x reference)
//
#include <hip/hip_runtime.h>
#include <cstdint>
#include <cstddef>

typedef _Float16 f16;
typedef _Float16 f16x2 __attribute__((ext_vector_type(2)));

constexpr int Bn = 64, In = 128, Tn = 1024, Hn = 256, Gn = 1024; // Gn = 4H

// ---------------- helpers ----------------

__device__ __forceinline__ float fdot2(f16x2 a, f16x2 b, float c) {
#if defined(__has_builtin)
#if __has_builtin(__builtin_amdgcn_fdot2)
  return __builtin_amdgcn_fdot2(a, b, c, false);
#else
  return c + (float)a.x * (float)b.x + (float)a.y * (float)b.y;
#endif
#else
  return c + (float)a.x * (float)b.x + (float)a.y * (float)b.y;
#endif
}

__device__ __forceinline__ float rcp_(float x) {
#if defined(__has_builtin)
#if __has_builtin(__builtin_amdgcn_rcpf)
  return __builtin_amdgcn_rcpf(x);
#else
  return 1.f / x;
#endif
#else
  return 1.f / x;
#endif
}

__device__ __forceinline__ float sigm(float x) {
  return rcp_(1.f + __expf(-x));
}

__device__ __forceinline__ float tanh_(float x) {
  float xc = fminf(fmaxf(x, -15.f), 15.f);
  float e = __expf(-2.f * xc);
  return (1.f - e) * rcp_(1.f + e);
}

#define BC2(x) __builtin_bit_cast(f16x2, x)

// ---------------- pack W_hh (f32 [1024][256]) into rec-kernel layout ----------------
// rec thread n owns gate-row n (i:0-255, f:256-511, g:512-767, o:768-1023).
// wregG[k*1024+n] (k<96)        = W_hh[n][cols 2k,2k+1]        (register-resident)
// wldsE[((q<<10)+n)*4+m] (q<8)  = W_hh[n][col2 96+4q+m]        (LDS-resident, cols 192..255)
__global__ void pack_whh(const float* __restrict__ Whh,
                         f16x2* __restrict__ wregG, f16x2* __restrict__ wldsE) {
  const int n = blockIdx.x;   // 0..1023 (gate-row)
  const int k = threadIdx.x;  // 0..127  (col2 index)
  const float2* w2 = (const float2*)Whh;
  float2 v = w2[(size_t)n * (Hn / 2) + k];
  f16x2 h; h.x = (f16)v.x; h.y = (f16)v.y;
  if (k < 96) {
    wregG[(size_t)k * 1024 + n] = h;
  } else {
    int idx = k - 96;                 // 0..31
    int q = idx >> 2, m = idx & 3;
    wldsE[((size_t)(q << 10) + n) * 4 + m] = h;
  }
}

// ---------------- input GEMM (segment): pre[b,tl,g] = sum_i x[b,i,tbase+tl]*W_ih[g,i] + b_ih[g]+b_hh[g]
__global__ __launch_bounds__(256, 4) void gemm_pre(
    const float* __restrict__ x, const float* __restrict__ Wih,
    const float* __restrict__ bih, const float* __restrict__ bhh,
    float* __restrict__ pre, int Ts, int tbase) {
  __shared__ float xs[64][64];   // [i][tt]
  __shared__ float wsh[64][65];  // [gg][i], padded
  const int bb = blockIdx.z, t0 = blockIdx.y * 64, g0 = blockIdx.x * 64;
  const int tid = threadIdx.x;
  const int tx = tid & 15, ty = tid >> 4;
  const int l64 = tid & 63, h2b = tid >> 6;
  float acc[4][4] = {};

  for (int ih = 0; ih < 2; ++ih) {
#pragma unroll 4
    for (int s = 0; s < 16; ++s) {
      int i = h2b + s * 4;
      xs[i][l64] = x[(size_t)bb * In * Tn + (size_t)(ih * 64 + i) * Tn + tbase + t0 + l64];
      wsh[i][l64] = Wih[(size_t)(g0 + i) * In + ih * 64 + l64];
    }
    __syncthreads();
#pragma unroll 8
    for (int i = 0; i < 64; ++i) {
      float4 xv = *(const float4*)&xs[i][ty * 4];
      float w0 = wsh[tx * 4 + 0][i];
      float w1 = wsh[tx * 4 + 1][i];
      float w2 = wsh[tx * 4 + 2][i];
      float w3 = wsh[tx * 4 + 3][i];
      acc[0][0] += xv.x * w0; acc[0][1] += xv.x * w1; acc[0][2] += xv.x * w2; acc[0][3] += xv.x * w3;
      acc[1][0] += xv.y * w0; acc[1][1] += xv.y * w1; acc[1][2] += xv.y * w2; acc[1][3] += xv.y * w3;
      acc[2][0] += xv.z * w0; acc[2][1] += xv.z * w1; acc[2][2] += xv.z * w2; acc[2][3] += xv.z * w3;
      acc[3][0] += xv.w * w0; acc[3][1] += xv.w * w1; acc[3][2] += xv.w * w2; acc[3][3] += xv.w * w3;
    }
    __syncthreads();
  }

  float bs[4];
#pragma unroll
  for (int q = 0; q < 4; ++q) {
    int g = g0 + tx * 4 + q;
    bs[q] = bih[g] + bhh[g];
  }
#pragma unroll
  for (int ti = 0; ti < 4; ++ti) {
    int tl = t0 + ty * 4 + ti;
    size_t idx = ((size_t)bb * Ts + tl) * Gn + g0 + tx * 4;
    float4 fv;
    fv.x = acc[ti][0] + bs[0]; fv.y = acc[ti][1] + bs[1];
    fv.z = acc[ti][2] + bs[2]; fv.w = acc[ti][3] + bs[3];
    *(float4*)&pre[idx] = fv;
  }
}

// ---------------- recurrent kernel: 1024 threads, 1 gate-row/thread ----------------
// Rounds 3/5/6: three occupancy-hint spellings all gave VGPR_Count=128 and a
// demoted 192-reg weight array (7.5ms, VALUBusy 1.9%). This version is designed
// to FIT 128 VGPRs: 96 *named* f16x2 weight values (no array -> no alloca) +
// 32 f16x2/thread in LDS. A 1024-thread block forces the <=128-VGPR budget
// anyway, so this works whether the cap was budget- or promotion-driven.
#define LDW(i) const f16x2 w##i = wregG[(size_t)(i) * 1024 + n];
#define DOT4(K0, K1, K2, K3, CC)            \
  {                                         \
    float4 hv = hv4[CC];                    \
    a0 = fdot2(w##K0, BC2(hv.x), a0);       \
    a1 = fdot2(w##K1, BC2(hv.y), a1);       \
    a0 = fdot2(w##K2, BC2(hv.z), a0);       \
    a1 = fdot2(w##K3, BC2(hv.w), a1);       \
  }

__global__ __launch_bounds__(1024, 1)
void lstm_rec(
    const f16x2* __restrict__ wregG, const float4* __restrict__ wldsG,
    const float* __restrict__ pre, float* __restrict__ out,
    float* __restrict__ cws, f16x2* __restrict__ hws,
    int seg0, int Ts, int tbase) {
  __shared__ float4 wl4[8 * 1024];          // 128KB (cols 192..255 of all rows)
  __shared__ __align__(16) f16 hbuf[256];   // 512B h-state
  __shared__ float gact[1024];              // 4KB activated gates
  __shared__ f16 hist[256 * 33];            // 16.9KB output staging (+1 pad col)

  const int n  = threadIdx.x;  // 0..1023 gate-row
  const int bb = blockIdx.x;   // batch element

  // 96 named register-resident weights (cols2 0..95)
  LDW(0)  LDW(1)  LDW(2)  LDW(3)  LDW(4)  LDW(5)  LDW(6)  LDW(7)
  LDW(8)  LDW(9)  LDW(10) LDW(11) LDW(12) LDW(13) LDW(14) LDW(15)
  LDW(16) LDW(17) LDW(18) LDW(19) LDW(20) LDW(21) LDW(22) LDW(23)
  LDW(24) LDW(25) LDW(26) LDW(27) LDW(28) LDW(29) LDW(30) LDW(31)
  LDW(32) LDW(33) LDW(34) LDW(35) LDW(36) LDW(37) LDW(38) LDW(39)
  LDW(40) LDW(41) LDW(42) LDW(43) LDW(44) LDW(45) LDW(46) LDW(47)
  LDW(48) LDW(49) LDW(50) LDW(51) LDW(52) LDW(53) LDW(54) LDW(55)
  LDW(56) LDW(57) LDW(58) LDW(59) LDW(60) LDW(61) LDW(62) LDW(63)
  LDW(64) LDW(65) LDW(66) LDW(67) LDW(68) LDW(69) LDW(70) LDW(71)
  LDW(72) LDW(73) LDW(74) LDW(75) LDW(76) LDW(77) LDW(78) LDW(79)
  LDW(80) LDW(81) LDW(82) LDW(83) LDW(84) LDW(85) LDW(86) LDW(87)
  LDW(88) LDW(89) LDW(90) LDW(91) LDW(92) LDW(93) LDW(94) LDW(95)

  // stage LDS-resident weights (cols2 96..127)
#pragma unroll
  for (int q = 0; q < 8; ++q) wl4[(q << 10) + n] = wldsG[(size_t)(q << 10) + n];

  f16x2* hbuf2 = (f16x2*)hbuf;
  if (n < 128) {
    f16x2 z = {};
    hbuf2[n] = seg0 ? z : hws[bb * 128 + n];
  }
  __syncthreads();

  const size_t pbase = (size_t)bb * Ts * Gn;
  float* outb = out + (size_t)bb * Hn * Tn + tbase;

  float c = 0.f;
  if (n < 256 && !seg0) c = cws[bb * 256 + n];
  float p = pre[pbase + n];

  const float4* hv4 = (const float4*)hbuf;

  for (int t = 0; t < Ts; ++t) {
    float a0 = 0.f, a1 = 0.f;
    // cols2 0..95 from registers (h broadcast-read from LDS)
    DOT4(0, 1, 2, 3, 0)     DOT4(4, 5, 6, 7, 1)     DOT4(8, 9, 10, 11, 2)   DOT4(12, 13, 14, 15, 3)
    DOT4(16, 17, 18, 19, 4) DOT4(20, 21, 22, 23, 5) DOT4(24, 25, 26, 27, 6) DOT4(28, 29, 30, 31, 7)
    DOT4(32, 33, 34, 35, 8) DOT4(36, 37, 38, 39, 9) DOT4(40, 41, 42, 43, 10) DOT4(44, 45, 46, 47, 11)
    DOT4(48, 49, 50, 51, 12) DOT4(52, 53, 54, 55, 13) DOT4(56, 57, 58, 59, 14) DOT4(60, 61, 62, 63, 15)
    DOT4(64, 65, 66, 67, 16) DOT4(68, 69, 70, 71, 17) DOT4(72, 73, 74, 75, 18) DOT4(76, 77, 78, 79, 19)
    DOT4(80, 81, 82, 83, 20) DOT4(84, 85, 86, 87, 21) DOT4(88, 89, 90, 91, 22) DOT4(92, 93, 94, 95, 23)
    // cols2 96..127 from LDS
#pragma unroll
    for (int q = 0; q < 8; ++q) {
      float4 wv = wl4[(q << 10) + n];
      float4 hv = hv4[24 + q];
      a0 = fdot2(BC2(wv.x), BC2(hv.x), a0);
      a1 = fdot2(BC2(wv.y), BC2(hv.y), a1);
      a0 = fdot2(BC2(wv.z), BC2(hv.z), a0);
      a1 = fdot2(BC2(wv.w), BC2(hv.w), a1);
    }
    float raw = a0 + a1 + p;

    // prefetch next step's pre
    if (t + 1 < Ts) p = pre[pbase + (size_t)(t + 1) * Gn + n];

    // activation (wave-uniform branch: quarter boundaries are multiples of 64)
    float act = (n >= 512 && n < 768) ? tanh_(raw) : sigm(raw);
    gact[n] = act;
    __syncthreads();

    if (n < 256) {
      c = gact[256 + n] * c + gact[n] * gact[512 + n];  // f*c + i*g
      float th = tanh_(c);
      float h = gact[768 + n] * th;                     // o*tanh(c)
      hist[n * 33 + (t & 31)] = (f16)fmaxf(h, 0.f);
      hbuf[n] = (f16)h;
    }
    __syncthreads();

    if ((t & 31) == 31) {
      int t0 = t - 31;
#pragma unroll
      for (int v = 0; v < 8; ++v) {
        int flat = (v << 10) + n;
        int row = flat >> 5, tt = flat & 31;
        outb[(size_t)row * Tn + t0 + tt] = (float)hist[row * 33 + tt];
      }
      // safe without extra barrier: next hist write is after next step's first barrier
    }
  }

  // persist state for next segment
  if (n < 256) cws[bb * 256 + n] = c;
  if (n < 128) hws[bb * 128 + n] = hbuf2[n];
}

// ---------------- launch ----------------
extern "C" void kernel_launch(void* const* d_in, const int* in_sizes, int n_in,
                              void* d_out, int out_size, void* d_ws, size_t ws_size,
                              hipStream_t stream) {
  const float* x   = (const float*)d_in[0];
  const float* Wih = (const float*)d_in[1];
  const float* Whh = (const float*)d_in[2];
  const float* bih = (const float*)d_in[3];
  const float* bhh = (const float*)d_in[4];
  float* out = (float*)d_out;
  char* ws = (char*)d_ws;

  f16x2* wregG = (f16x2*)ws;                   // 96*1024*4 = 384KB
  f16x2* wldsE = (f16x2*)(ws + 384 * 1024);    // 8*1024*16 = 128KB -> 512KB
  float* cws   = (float*)(ws + 512 * 1024);    // 64KB  -> 576KB
  f16x2* hws   = (f16x2*)(ws + 576 * 1024);    // 32KB  -> 608KB
  float* pre   = (float*)(ws + (1 << 20));     // segment pre buffer

  // choose largest segment length whose fp32 pre fits in ws
  int Ts = 64;
  for (int cand = 1024; cand >= 64; cand >>= 1) {
    size_t need = (size_t)(1 << 20) + (size_t)Bn * cand * Gn * 4;
    if (need <= ws_size) { Ts = cand; break; }
  }
  int nseg = Tn / Ts;

  pack_whh<<<dim3(1024), dim3(128), 0, stream>>>(Whh, wregG, wldsE);

  for (int s = 0; s < nseg; ++s) {
    dim3 gg(16, Ts / 64, 64);
    gemm_pre<<<gg, dim3(256), 0, stream>>>(x, Wih, bih, bhh, pre, Ts, s * Ts);
    lstm_rec<<<dim3(64), dim3(1024), 0, stream>>>(
        wregG, (const float4*)wldsE, pre, out, cws, hws, (s == 0) ? 1 : 0, Ts, s * Ts);
  }
}